// Round 1
// baseline (754.704 us; speedup 1.0000x reference)
//
#include <hip/hip_runtime.h>
#include <math.h>

#define B_ 4
#define L_ 4800
#define S_ 4800
#define C_ 256
#define THR 0.2f
#define SIM_SCALE 0.0390625f   // 1/(256*0.1)
#define KPT_SCALE 8.0f

typedef short bf16x8 __attribute__((ext_vector_type(8)));   // 8 bf16 in 4 VGPRs
typedef float f32x4  __attribute__((ext_vector_type(4)));

// ---------------- ws layout (floats) ----------------
// [0,19200)       rowsum      (B*L)
// [19200,38400)   colsum      (B*S)
// [38400,57600)   rowmax      (B*L)
// [57600,76800)   colmax      (B*S)
// [76800, ...)    f0b bf16 (B*L*C), then f1b bf16 (B*S*C)

__device__ __forceinline__ unsigned short f2bf(float x) {
    union { float f; unsigned int u; } v; v.f = x;
    unsigned int r = v.u + 0x7fffu + ((v.u >> 16) & 1u);   // RNE
    return (unsigned short)(r >> 16);
}

__global__ void k_init(float* ws) {
    int i = blockIdx.x * blockDim.x + threadIdx.x;
    if (i < 76800) ws[i] = 0.0f;
}

__global__ void k_cast(const float* __restrict__ f0, const float* __restrict__ f1,
                       ushort* __restrict__ f0b, ushort* __restrict__ f1b) {
    int i = blockIdx.x * blockDim.x + threadIdx.x;   // float4 index
    if (i * 4 >= B_ * L_ * C_) return;
    float4 a = ((const float4*)f0)[i];
    float4 b = ((const float4*)f1)[i];
    ushort4 oa, ob;
    oa.x = f2bf(a.x); oa.y = f2bf(a.y); oa.z = f2bf(a.z); oa.w = f2bf(a.w);
    ob.x = f2bf(b.x); ob.y = f2bf(b.y); ob.z = f2bf(b.z); ob.w = f2bf(b.w);
    ((ushort4*)f0b)[i] = oa;
    ((ushort4*)f1b)[i] = ob;
}

// sim GEMM: each wave computes a 64x64 tile of p = exp(sim); block = 4 waves
// covering 64(l) x 256(s). Writes p into conf region, accumulates row/col sums.
__global__ __launch_bounds__(256) void k_gemm(
        const ushort* __restrict__ f0b, const ushort* __restrict__ f1b,
        float* __restrict__ p_out,
        float* __restrict__ rowsum, float* __restrict__ colsum) {
    const int b    = blockIdx.z;
    const int l0   = blockIdx.y * 64;
    const int wave = threadIdx.x >> 6;
    const int s0   = blockIdx.x * 256 + wave * 64;
    if (s0 >= S_) return;                       // no __syncthreads in kernel: safe
    const int lane = threadIdx.x & 63;
    const int quad = lane >> 4;
    const int lr   = lane & 15;

    const ushort* A  = f0b + (size_t)b * L_ * C_;
    const ushort* Bm = f1b + (size_t)b * S_ * C_;

    f32x4 acc[4][4];
#pragma unroll
    for (int r = 0; r < 4; r++)
#pragma unroll
        for (int c = 0; c < 4; c++) acc[r][c] = (f32x4){0.f, 0.f, 0.f, 0.f};

    for (int kk = 0; kk < C_; kk += 32) {
        bf16x8 af[4], bf[4];
#pragma unroll
        for (int r = 0; r < 4; r++) {
            const int row = l0 + r * 16 + lr;                // A[m=lane&15][k=quad*8+j]
            af[r] = *(const bf16x8*)(A + (size_t)row * C_ + kk + quad * 8);
        }
#pragma unroll
        for (int c = 0; c < 4; c++) {
            const int srow = s0 + c * 16 + lr;               // B[k=quad*8+j][n=lane&15]
            bf[c] = *(const bf16x8*)(Bm + (size_t)srow * C_ + kk + quad * 8);
        }
#pragma unroll
        for (int r = 0; r < 4; r++)
#pragma unroll
            for (int c = 0; c < 4; c++)
                acc[r][c] = __builtin_amdgcn_mfma_f32_16x16x32_bf16(af[r], bf[c], acc[r][c], 0, 0, 0);
    }

    // p = exp(sim)
#pragma unroll
    for (int r = 0; r < 4; r++)
#pragma unroll
        for (int c = 0; c < 4; c++)
#pragma unroll
            for (int g = 0; g < 4; g++)
                acc[r][c][g] = __expf(acc[r][c][g] * SIM_SCALE);

    // store p: D layout col=lane&15 (s), row=quad*4+reg (l)
    float* pb = p_out + (size_t)b * L_ * S_;
#pragma unroll
    for (int r = 0; r < 4; r++)
#pragma unroll
        for (int g = 0; g < 4; g++) {
            const int row = l0 + r * 16 + quad * 4 + g;
            float* prow = pb + (size_t)row * S_ + s0 + lr;
#pragma unroll
            for (int c = 0; c < 4; c++) prow[c * 16] = acc[r][c][g];
        }

    // row sums (over this wave's 64 s-cols): reduce over c and the 16 lanes lr
#pragma unroll
    for (int r = 0; r < 4; r++)
#pragma unroll
        for (int g = 0; g < 4; g++) {
            float v = acc[r][0][g] + acc[r][1][g] + acc[r][2][g] + acc[r][3][g];
            v += __shfl_xor(v, 1, 64);
            v += __shfl_xor(v, 2, 64);
            v += __shfl_xor(v, 4, 64);
            v += __shfl_xor(v, 8, 64);
            if (lr == 0) {
                const int row = l0 + r * 16 + quad * 4 + g;
                atomicAdd(rowsum + b * L_ + row, v);
            }
        }
    // col sums (over this wave's 64 l-rows): reduce over r,g and the 4 quads
#pragma unroll
    for (int c = 0; c < 4; c++) {
        float v = 0.f;
#pragma unroll
        for (int r = 0; r < 4; r++)
#pragma unroll
            for (int g = 0; g < 4; g++) v += acc[r][c][g];
        v += __shfl_xor(v, 16, 64);
        v += __shfl_xor(v, 32, 64);
        if (quad == 0) atomicAdd(colsum + b * S_ + s0 + c * 16 + lr, v);
    }
}

// conf = p^2/(rowsum*colsum) in place, per-64x64-tile row/col max via LDS+global atomicMax
__global__ __launch_bounds__(256) void k_conf(
        float* __restrict__ conf,
        const float* __restrict__ rowsum, const float* __restrict__ colsum,
        float* __restrict__ rowmax, float* __restrict__ colmax) {
    const int b  = blockIdx.z;
    const int l0 = blockIdx.y * 64;
    const int s0 = blockIdx.x * 64;
    __shared__ unsigned rm[64], cm[64];
    const int t = threadIdx.x;
    if (t < 64) { rm[t] = 0u; cm[t] = 0u; }
    __syncthreads();
    const int c4 = t & 15, r0 = t >> 4;
    const float4 cs = *(const float4*)(colsum + b * S_ + s0 + c4 * 4);
    const float icx = 1.0f / cs.x, icy = 1.0f / cs.y, icz = 1.0f / cs.z, icw = 1.0f / cs.w;
    float cmx = 0.f, cmy = 0.f, cmz = 0.f, cmw = 0.f;
    float* base = conf + (size_t)b * L_ * S_;
#pragma unroll
    for (int it = 0; it < 4; it++) {
        const int r = r0 + 16 * it;
        const int l = l0 + r;
        const float irs = 1.0f / rowsum[b * L_ + l];
        float* addr = base + (size_t)l * S_ + s0 + c4 * 4;
        float4 p = *(float4*)addr;
        float4 cf;
        cf.x = p.x * p.x * (irs * icx);
        cf.y = p.y * p.y * (irs * icy);
        cf.z = p.z * p.z * (irs * icz);
        cf.w = p.w * p.w * (irs * icw);
        *(float4*)addr = cf;
        const float m = fmaxf(fmaxf(cf.x, cf.y), fmaxf(cf.z, cf.w));
        atomicMax(&rm[r], __float_as_uint(m));
        cmx = fmaxf(cmx, cf.x); cmy = fmaxf(cmy, cf.y);
        cmz = fmaxf(cmz, cf.z); cmw = fmaxf(cmw, cf.w);
    }
    atomicMax(&cm[c4 * 4 + 0], __float_as_uint(cmx));
    atomicMax(&cm[c4 * 4 + 1], __float_as_uint(cmy));
    atomicMax(&cm[c4 * 4 + 2], __float_as_uint(cmz));
    atomicMax(&cm[c4 * 4 + 3], __float_as_uint(cmw));
    __syncthreads();
    if (t < 64) {
        atomicMax((unsigned*)rowmax + b * L_ + l0 + t, rm[t]);
        atomicMax((unsigned*)colmax + b * S_ + s0 + t, cm[t]);
    }
}

// per-(b,l): first-index argmax of score, emit match/s_ids/mconf/mkpts
__global__ __launch_bounds__(256) void k_match(
        const float* __restrict__ conf,
        const float* __restrict__ rowmax, const float* __restrict__ colmax,
        float* __restrict__ o_match, float* __restrict__ o_sids,
        float* __restrict__ o_mconf, float* __restrict__ o_kp0,
        float* __restrict__ o_kp1) {
    const int l = blockIdx.x;
    const int b = blockIdx.y;
    const int t = threadIdx.x;
    const int lh = l / 80, lw = l % 80;
    const bool lvalid = (lh >= 2 && lh < 58 && lw >= 2 && lw < 78);

    __shared__ float sv[256];
    __shared__ int   si[256];

    float bv = 0.0f; int bi = 0;
    if (lvalid) {
        const float* row = conf + ((size_t)b * L_ + l) * S_;
        const float  rmv = rowmax[b * L_ + l];
        const float* cmr = colmax + b * S_;
        for (int i = t; i < S_ / 4; i += 256) {
            const float4 cf = *(const float4*)(row + i * 4);
            float cv; int s;
#define PROC(comp, off)                                                        \
            cv = cf.comp; s = i * 4 + off;                                     \
            if (cv > THR) {                                                    \
                const int sh = s / 80, sw = s % 80;                            \
                if (sh >= 2 && sh < 58 && sw >= 2 && sw < 78) {                \
                    const float sc = rmv * cmr[s];                             \
                    if (sc > bv || (sc == bv && s < bi)) { bv = sc; bi = s; }  \
                }                                                              \
            }
            PROC(x, 0) PROC(y, 1) PROC(z, 2) PROC(w, 3)
#undef PROC
        }
    }
    sv[t] = bv; si[t] = bi;
    __syncthreads();
    for (int off = 128; off > 0; off >>= 1) {
        if (t < off) {
            const float v2 = sv[t + off]; const int i2 = si[t + off];
            if (v2 > sv[t] || (v2 == sv[t] && i2 < si[t])) { sv[t] = v2; si[t] = i2; }
        }
        __syncthreads();
    }
    if (t == 0) {
        const float maxv = sv[0]; const int sid = si[0];
        const bool match = maxv > 0.0f;
        float mc = 0.0f;
        if (match) mc = conf[((size_t)b * L_ + l) * S_ + sid];
        const int o = b * L_ + l;
        o_match[o] = match ? 1.0f : 0.0f;
        o_sids[o]  = (float)sid;
        o_mconf[o] = mc;
        o_kp1[o * 2 + 0] = (float)(sid % 80) * KPT_SCALE;
        o_kp1[o * 2 + 1] = (float)(sid / 80) * KPT_SCALE;
        if (b == 0) {
            o_kp0[l * 2 + 0] = (float)lw * KPT_SCALE;
            o_kp0[l * 2 + 1] = (float)lh * KPT_SCALE;
        }
    }
}

extern "C" void kernel_launch(void* const* d_in, const int* in_sizes, int n_in,
                              void* d_out, int out_size, void* d_ws, size_t ws_size,
                              hipStream_t stream) {
    const float* f0 = (const float*)d_in[0];
    const float* f1 = (const float*)d_in[1];
    float* out = (float*)d_out;

    float* conf_o  = out;                       // B*L*S = 92,160,000
    float* o_match = out + (size_t)92160000;    // B*L
    float* o_sids  = o_match + 19200;
    float* o_mconf = o_sids + 19200;
    float* o_kp0   = o_mconf + 19200;           // L*2
    float* o_kp1   = o_kp0 + 9600;              // B*L*2

    float* wsf    = (float*)d_ws;
    float* rowsum = wsf;
    float* colsum = wsf + 19200;
    float* rowmax = wsf + 38400;
    float* colmax = wsf + 57600;
    ushort* f0b = (ushort*)(wsf + 76800);
    ushort* f1b = f0b + (size_t)B_ * L_ * C_;

    k_init<<<300, 256, 0, stream>>>(wsf);
    k_cast<<<4800, 256, 0, stream>>>(f0, f1, f0b, f1b);
    k_gemm<<<dim3(19, 75, B_), 256, 0, stream>>>(f0b, f1b, conf_o, rowsum, colsum);
    k_conf<<<dim3(75, 75, B_), 256, 0, stream>>>(conf_o, rowsum, colsum, rowmax, colmax);
    k_match<<<dim3(L_, B_), 256, 0, stream>>>(conf_o, rowmax, colmax,
                                              o_match, o_sids, o_mconf, o_kp0, o_kp1);
}